// Round 1
// baseline (1158.309 us; speedup 1.0000x reference)
//
#include <hip/hip_runtime.h>

static constexpr float EPS = 1e-6f;

// One block = one 64-lane wave = one batch element's sequential chain.
// Lane i owns row i of the fast-weight matrix M (64 fp32 VGPRs).
__global__ __launch_bounds__(64, 1)
void delta_mem_seq(const float* __restrict__ h,
                   const float* __restrict__ W,
                   const float* __restrict__ bias,
                   float* __restrict__ out,
                   int L) {
    const int b = blockIdx.x;
    const int lane = threadIdx.x;
    __shared__ alignas(16) float kbuf[2][64];
    __shared__ alignas(16) float rbuf[64];

    const float* __restrict__ hb = h + (size_t)b * (size_t)L * 64;

    float m[64];
#pragma unroll
    for (int j = 0; j < 64; ++j) m[j] = 0.f;

    float kself = hb[lane];  // k element for t=0 (coalesced)

    for (int t = 0; t < L - 1; ++t) {
        // stage k into LDS (double-buffered so no barrier needed before write)
        kbuf[t & 1][lane] = kself;
        // prefetch next step's k element early (hides HBM/L2 latency under compute)
        float knext = hb[(size_t)(t + 1) * 64 + lane];

        // denom = ||k||^2 (+eps later): butterfly on own element, overlaps with staging
        float s2 = kself * kself;
#pragma unroll
        for (int off = 32; off > 0; off >>= 1)
            s2 += __shfl_xor(s2, off, 64);

        __syncthreads();  // k staged -> visible

        // broadcast-read all of k into registers (16 x float4, conflict-free)
        const float4* kv = reinterpret_cast<const float4*>(kbuf[t & 1]);
        float4 kq[16];
#pragma unroll
        for (int q = 0; q < 16; ++q) kq[q] = kv[q];

        // v_pred[lane] = sum_j M[lane][j] * k[j]  (4 accumulators for ILP)
        float vp0 = 0.f, vp1 = 0.f, vp2 = 0.f, vp3 = 0.f;
#pragma unroll
        for (int q = 0; q < 16; ++q) {
            vp0 = fmaf(m[4 * q + 0], kq[q].x, vp0);
            vp1 = fmaf(m[4 * q + 1], kq[q].y, vp1);
            vp2 = fmaf(m[4 * q + 2], kq[q].z, vp2);
            vp3 = fmaf(m[4 * q + 3], kq[q].w, vp3);
        }
        float vp = (vp0 + vp1) + (vp2 + vp3);

        // u = k - v_pred/denom  (per-lane element i)
        float u = kself - vp / (s2 + EPS);

        // gate: ||M+dM||^2 > ||M||^2  <=>  2*dot(u,v_pred) + ||u||^2*||k||^2 > 0
        float duv = u * vp;
        float uu = u * u;
#pragma unroll
        for (int off = 32; off > 0; off >>= 1) {
            duv += __shfl_xor(duv, off, 64);
            uu  += __shfl_xor(uu,  off, 64);
        }
        float gu = (2.f * duv + uu * s2 > 0.f) ? u : 0.f;

        // rank-1 update: M[lane][j] += gu * k[j]
#pragma unroll
        for (int q = 0; q < 16; ++q) {
            m[4 * q + 0] = fmaf(gu, kq[q].x, m[4 * q + 0]);
            m[4 * q + 1] = fmaf(gu, kq[q].y, m[4 * q + 1]);
            m[4 * q + 2] = fmaf(gu, kq[q].z, m[4 * q + 2]);
            m[4 * q + 3] = fmaf(gu, kq[q].w, m[4 * q + 3]);
        }
        kself = knext;
    }

    // epilogue: read = M @ h_last  (kself holds h[b][L-1][lane])
    __syncthreads();  // last loop reads of kbuf done before reuse
    kbuf[0][lane] = kself;
    __syncthreads();
    {
        const float4* kv = reinterpret_cast<const float4*>(kbuf[0]);
        float vp0 = 0.f, vp1 = 0.f, vp2 = 0.f, vp3 = 0.f;
#pragma unroll
        for (int q = 0; q < 16; ++q) {
            float4 kq = kv[q];
            vp0 = fmaf(m[4 * q + 0], kq.x, vp0);
            vp1 = fmaf(m[4 * q + 1], kq.y, vp1);
            vp2 = fmaf(m[4 * q + 2], kq.z, vp2);
            vp3 = fmaf(m[4 * q + 3], kq.w, vp3);
        }
        rbuf[lane] = (vp0 + vp1) + (vp2 + vp3);
    }
    __syncthreads();

    // out[b][o] = sum_i read[i] * W[o][i] + bias[o]   (lane = o; W row contiguous)
    const float4* wv = reinterpret_cast<const float4*>(W + lane * 64);
    const float4* rv = reinterpret_cast<const float4*>(rbuf);
    float acc = bias[lane];
#pragma unroll
    for (int q = 0; q < 16; ++q) {
        float4 wq = wv[q];
        float4 rq = rv[q];
        acc = fmaf(wq.x, rq.x, acc);
        acc = fmaf(wq.y, rq.y, acc);
        acc = fmaf(wq.z, rq.z, acc);
        acc = fmaf(wq.w, rq.w, acc);
    }
    out[(size_t)b * 64 + lane] = acc;
}

extern "C" void kernel_launch(void* const* d_in, const int* in_sizes, int n_in,
                              void* d_out, int out_size, void* d_ws, size_t ws_size,
                              hipStream_t stream) {
    const float* h    = (const float*)d_in[0];
    const float* W    = (const float*)d_in[1];
    const float* bias = (const float*)d_in[2];
    float* out = (float*)d_out;

    const int H = in_sizes[2];            // 64
    const int B = out_size / H;           // 256
    const int L = in_sizes[0] / (B * H);  // 2048

    delta_mem_seq<<<B, 64, 0, stream>>>(h, W, bias, out, L);
}